// Round 4
// baseline (326.789 us; speedup 1.0000x reference)
//
#include <hip/hip_runtime.h>

#define Kk  16
#define Bb  2048
#define Dd  1024
#define dd_ 64
#define BT  64
#define ECH 16      // encode D-chunk per wave
#define DCH 32      // decode D-chunk per wave
#define XPAD 20     // x_chunk row stride (floats): 5 f4 -> distinct banks per lb
#define UPAD 68     // Us/z row stride (floats): 17 f4 -> distinct banks per row

// ---------------------------------------------------------------------------
// Fused encode+decode per (k, 64-b tile). 256 thr = 4 waves.
// Encode: wave w reduces D in [w*256,(w+1)*256) with 8x8 lane tiles into
//   acc[8][8]; partials reduced through LDS into zbuf[b][d] (+znorm,+xnorm).
// Decode: wave w produces D-cols [w*256..) in chunks of 32, 8x8x... lane tile
//   dacc[8b][4D], z rows read straight from zbuf (8-distinct x 8-bcast reads).
// lterm = ||xhat||^2 - 2||z||^2  (losses = xnorm + lterm).
// ---------------------------------------------------------------------------
__global__ __launch_bounds__(256) void k_fused(const float* __restrict__ x,
                                               const float* __restrict__ Us,
                                               float* __restrict__ xhat,
                                               float* __restrict__ xnorm,
                                               float* __restrict__ lterm) {
    __shared__ float zbuf[BT * UPAD];   // z [b][d] (also wave0's partial)
    __shared__ float U[13056];          // union: enc staging / dec staging / partials 1..3
    __shared__ float zn_lds[BT], hat_lds[BT], xn_lds[BT];

    const int t    = threadIdx.x;
    const int lane = t & 63;
    const int w    = t >> 6;
    const int lb   = lane >> 3;   // 8 b-groups (distinct-address dim)
    const int ld   = lane & 7;    // 8 d-groups (broadcast dim / contig stores)

    const int bid = blockIdx.x;
    const int sw  = (bid & 7) * 64 + (bid >> 3);   // XCD swizzle, bijective
    const int k   = sw >> 5;
    const int b0  = (sw & 31) * BT;

    const float* __restrict__ xk  = x  + (size_t)b0 * Dd;
    const float* __restrict__ Usk = Us + (size_t)k * Dd * dd_;

    if (t < BT) { zn_lds[t] = 0.f; hat_lds[t] = 0.f; xn_lds[t] = 0.f; }
    __syncthreads();

    // ======================= encode =======================
    float* xch = U + w * 2368;          // [64][XPAD]
    float* uch = U + w * 2368 + 1280;   // [ECH][UPAD]
    const int Dbase = w * 256;

    float acc[8][8];
#pragma unroll
    for (int i = 0; i < 8; ++i)
#pragma unroll
        for (int j = 0; j < 8; ++j) acc[i][j] = 0.f;

    const int urow = lane >> 2;          // Us staging row 0..15
    const int ucol = (lane & 3) * 16;    // 16-float slice
    float4 px[4], pu[4];
#pragma unroll
    for (int c = 0; c < 4; ++c) {
        px[c] = *reinterpret_cast<const float4*>(xk + (size_t)lane * Dd + Dbase + c * 4);
        pu[c] = *reinterpret_cast<const float4*>(Usk + (size_t)(Dbase + urow) * dd_ + ucol + c * 4);
    }
    float xsq = 0.f;

    for (int ch = 0; ch < 16; ++ch) {
        // stage current chunk from regs
#pragma unroll
        for (int c = 0; c < 4; ++c) {
            *reinterpret_cast<float4*>(&xch[lane * XPAD + c * 4]) = px[c];
            *reinterpret_cast<float4*>(&uch[urow * UPAD + ucol + c * 4]) = pu[c];
            xsq = fmaf(px[c].x, px[c].x, xsq); xsq = fmaf(px[c].y, px[c].y, xsq);
            xsq = fmaf(px[c].z, px[c].z, xsq); xsq = fmaf(px[c].w, px[c].w, xsq);
        }
        // prefetch next chunk (flies under compute)
        if (ch < 15) {
            int Dn = Dbase + (ch + 1) * ECH;
#pragma unroll
            for (int c = 0; c < 4; ++c) {
                px[c] = *reinterpret_cast<const float4*>(xk + (size_t)lane * Dd + Dn + c * 4);
                pu[c] = *reinterpret_cast<const float4*>(Usk + (size_t)(Dn + urow) * dd_ + ucol + c * 4);
            }
        }
        // compute 16 kk: a = x[8b][4kk] col-reads, b = Us[kk][8d] row-reads
#pragma unroll
        for (int kb = 0; kb < 4; ++kb) {
            float af[8][4];
#pragma unroll
            for (int r = 0; r < 8; ++r) {
                float4 v = *reinterpret_cast<const float4*>(&xch[(8 * r + lb) * XPAD + kb * 4]);
                af[r][0] = v.x; af[r][1] = v.y; af[r][2] = v.z; af[r][3] = v.w;
            }
#pragma unroll
            for (int k2 = 0; k2 < 4; ++k2) {
                float4 b0v = *reinterpret_cast<const float4*>(&uch[(kb * 4 + k2) * UPAD + ld * 8]);
                float4 b1v = *reinterpret_cast<const float4*>(&uch[(kb * 4 + k2) * UPAD + ld * 8 + 4]);
                float bb[8] = {b0v.x, b0v.y, b0v.z, b0v.w, b1v.x, b1v.y, b1v.z, b1v.w};
#pragma unroll
                for (int r = 0; r < 8; ++r)
#pragma unroll
                    for (int j = 0; j < 8; ++j)
                        acc[r][j] = fmaf(af[r][k2], bb[j], acc[r][j]);
            }
        }
    }
    atomicAdd(&xn_lds[lane], xsq);
    __syncthreads();   // all encode compute done; staging regions now dead

    // write K-partials [b][d] (wave0 direct to zbuf)
    {
        float* pw = (w == 0) ? zbuf : (U + (w - 1) * 4352);
#pragma unroll
        for (int r = 0; r < 8; ++r) {
            float4 lo = make_float4(acc[r][0], acc[r][1], acc[r][2], acc[r][3]);
            float4 hi = make_float4(acc[r][4], acc[r][5], acc[r][6], acc[r][7]);
            *reinterpret_cast<float4*>(&pw[(8 * r + lb) * UPAD + ld * 8])     = lo;
            *reinterpret_cast<float4*>(&pw[(8 * r + lb) * UPAD + ld * 8 + 4]) = hi;
        }
    }
    __syncthreads();

    // reduce 4 partials -> zbuf; znorm
    {
        const int b = t >> 2, d0 = (t & 3) * 16;
        float4 s[4];
#pragma unroll
        for (int c = 0; c < 4; ++c)
            s[c] = *reinterpret_cast<const float4*>(&zbuf[b * UPAD + d0 + c * 4]);
#pragma unroll
        for (int w2 = 0; w2 < 3; ++w2)
#pragma unroll
            for (int c = 0; c < 4; ++c) {
                float4 p = *reinterpret_cast<const float4*>(&U[w2 * 4352 + b * UPAD + d0 + c * 4]);
                s[c].x += p.x; s[c].y += p.y; s[c].z += p.z; s[c].w += p.w;
            }
        float zq = 0.f;
#pragma unroll
        for (int c = 0; c < 4; ++c) {
            *reinterpret_cast<float4*>(&zbuf[b * UPAD + d0 + c * 4]) = s[c];
            zq = fmaf(s[c].x, s[c].x, zq); zq = fmaf(s[c].y, s[c].y, zq);
            zq = fmaf(s[c].z, s[c].z, zq); zq = fmaf(s[c].w, s[c].w, zq);
        }
        zq += __shfl_xor(zq, 1, 64);
        zq += __shfl_xor(zq, 2, 64);
        if ((t & 3) == 0) zn_lds[b] = zq;
    }
    if (k == 0 && t < BT) xnorm[b0 + t] = xn_lds[t];
    __syncthreads();

    // ======================= decode =======================
    float* uw = U + w * 2176;   // [DCH][UPAD]
    const int r2 = lane >> 1;            // staging row 0..31
    const int c2 = (lane & 1) * 32;
    float hat[8];
#pragma unroll
    for (int r = 0; r < 8; ++r) hat[r] = 0.f;

    float4 pv[8];
#pragma unroll
    for (int c = 0; c < 8; ++c)
        pv[c] = *reinterpret_cast<const float4*>(Usk + (size_t)(w * 256 + r2) * dd_ + c2 + c * 4);

    for (int ch = 0; ch < 8; ++ch) {
        const int Dc = w * 256 + ch * DCH;
#pragma unroll
        for (int c = 0; c < 8; ++c)
            *reinterpret_cast<float4*>(&uw[r2 * UPAD + c2 + c * 4]) = pv[c];
        if (ch < 7) {
#pragma unroll
            for (int c = 0; c < 8; ++c)
                pv[c] = *reinterpret_cast<const float4*>(Usk + (size_t)(Dc + DCH + r2) * dd_ + c2 + c * 4);
        }
        float dacc[8][4];
#pragma unroll
        for (int r = 0; r < 8; ++r)
#pragma unroll
            for (int s = 0; s < 4; ++s) dacc[r][s] = 0.f;

#pragma unroll
        for (int kb = 0; kb < 16; ++kb) {
            float af[8][4];
#pragma unroll
            for (int r = 0; r < 8; ++r) {
                float4 v = *reinterpret_cast<const float4*>(&zbuf[(8 * r + lb) * UPAD + kb * 4]);
                af[r][0] = v.x; af[r][1] = v.y; af[r][2] = v.z; af[r][3] = v.w;
            }
            float bf[4][4];
#pragma unroll
            for (int s = 0; s < 4; ++s) {
                float4 v = *reinterpret_cast<const float4*>(&uw[(8 * s + ld) * UPAD + kb * 4]);
                bf[s][0] = v.x; bf[s][1] = v.y; bf[s][2] = v.z; bf[s][3] = v.w;
            }
#pragma unroll
            for (int k2 = 0; k2 < 4; ++k2)
#pragma unroll
                for (int r = 0; r < 8; ++r)
#pragma unroll
                    for (int s = 0; s < 4; ++s)
                        dacc[r][s] = fmaf(af[r][k2], bf[s][k2], dacc[r][s]);
        }
        // stores (8-float segments across ld) + hat
#pragma unroll
        for (int r = 0; r < 8; ++r) {
            float* xr = xhat + (size_t)(k * Bb + b0 + 8 * r + lb) * Dd + Dc + ld;
#pragma unroll
            for (int s = 0; s < 4; ++s) {
                xr[8 * s] = dacc[r][s];
                hat[r] = fmaf(dacc[r][s], dacc[r][s], hat[r]);
            }
        }
    }
#pragma unroll
    for (int r = 0; r < 8; ++r) {
        hat[r] += __shfl_xor(hat[r], 1, 64);
        hat[r] += __shfl_xor(hat[r], 2, 64);
        hat[r] += __shfl_xor(hat[r], 4, 64);
    }
    if (ld == 0) {
#pragma unroll
        for (int r = 0; r < 8; ++r) atomicAdd(&hat_lds[8 * r + lb], hat[r]);
    }
    __syncthreads();
    if (t < BT) lterm[k * Bb + b0 + t] = hat_lds[t] - 2.f * zn_lds[t];
}

// ---------------------------------------------------------------------------
// Assign: tiny now (reads lterm + xnorm only).
// ---------------------------------------------------------------------------
__global__ __launch_bounds__(128) void k_assign(const float* __restrict__ xnorm,
                                                const float* __restrict__ lterm,
                                                float* __restrict__ c,
                                                float* __restrict__ cnt_part,
                                                float* __restrict__ obj_part) {
    __shared__ float cnt[Kk];
    __shared__ float objacc;
    const int t = threadIdx.x;
    const int b = blockIdx.x * 128 + t;
    if (t < Kk) cnt[t] = 0.f;
    if (t == 0) objacc = 0.f;
    __syncthreads();

    float xn   = xnorm[b];
    float best = 3.4e38f;
    int   bi   = 0;
#pragma unroll
    for (int k = 0; k < Kk; ++k) {
        float l = xn + lterm[k * Bb + b];
        if (l < best) { best = l; bi = k; }   // strict < == first argmin
    }
#pragma unroll
    for (int j = 0; j < 4; ++j) {
        float4 o;
        o.x = (bi == j * 4 + 0) ? 1.f : 0.f;
        o.y = (bi == j * 4 + 1) ? 1.f : 0.f;
        o.z = (bi == j * 4 + 2) ? 1.f : 0.f;
        o.w = (bi == j * 4 + 3) ? 1.f : 0.f;
        *reinterpret_cast<float4*>(&c[(size_t)b * Kk + j * 4]) = o;
    }
    atomicAdd(&cnt[bi], 1.f);

    float lobj = best;
#pragma unroll
    for (int off = 32; off > 0; off >>= 1) lobj += __shfl_down(lobj, off, 64);
    if ((t & 63) == 0) atomicAdd(&objacc, lobj);
    __syncthreads();

    if (t < Kk) cnt_part[blockIdx.x * Kk + t] = cnt[t];
    if (t == 0) obj_part[blockIdx.x] = objacc;
}

// ---------------------------------------------------------------------------
__global__ __launch_bounds__(64) void k_final(const float* __restrict__ cnt_part,
                                              const float* __restrict__ obj_part,
                                              const float* __restrict__ c_mean,
                                              float* __restrict__ c_mean_new,
                                              float* __restrict__ obj) {
    const int t = threadIdx.x;
    if (t < Kk) {
        float s = 0.f;
#pragma unroll
        for (int p = 0; p < 16; ++p) s += cnt_part[p * Kk + t];
        c_mean_new[t] = 0.9f * c_mean[t] + 0.1f * (s * (1.f / Bb));
    }
    if (t == 0) {
        float s = 0.f;
#pragma unroll
        for (int p = 0; p < 16; ++p) s += obj_part[p];
        obj[0] = s * (1.f / Bb);
    }
}

// ---------------------------------------------------------------------------
extern "C" void kernel_launch(void* const* d_in, const int* in_sizes, int n_in,
                              void* d_out, int out_size, void* d_ws, size_t ws_size,
                              hipStream_t stream) {
    const float* x      = (const float*)d_in[0];
    const float* Us     = (const float*)d_in[1];
    const float* c_mean = (const float*)d_in[2];

    float* out        = (float*)d_out;
    float* xhat       = out;                              // K*B*D
    float* c          = out + (size_t)Kk * Bb * Dd;       // B*K
    float* c_mean_new = c + (size_t)Bb * Kk;              // K
    float* obj        = c_mean_new + Kk;                  // 1

    float* ws       = (float*)d_ws;
    float* lterm    = ws;                                 // K*B
    float* xnorm    = lterm + (size_t)Kk * Bb;            // B
    float* cnt_part = xnorm + Bb;                         // 16*K
    float* obj_part = cnt_part + 16 * Kk;                 // 16

    k_fused <<<Kk * (Bb / BT), 256, 0, stream>>>(x, Us, xhat, xnorm, lterm);
    k_assign<<<Bb / 128, 128, 0, stream>>>(xnorm, lterm, c, cnt_part, obj_part);
    k_final <<<1, 64, 0, stream>>>(cnt_part, obj_part, c_mean, c_mean_new, obj);
}

// Round 5
// 227.555 us; speedup vs baseline: 1.4361x; 1.4361x over previous
//
#include <hip/hip_runtime.h>

#define Kk 16
#define Bb 2048
#define Dd 1024

typedef __attribute__((ext_vector_type(8))) short short8;
typedef __attribute__((ext_vector_type(4))) float f32x4;
typedef __attribute__((ext_vector_type(4))) unsigned short us4;
typedef unsigned short ushort_t;

__device__ __forceinline__ unsigned short bfhi(float f) {
    union { float f; unsigned u; } v; v.f = f;
    unsigned u = v.u + 0x7fffu + ((v.u >> 16) & 1u);
    return (unsigned short)(u >> 16);
}
__device__ __forceinline__ float bf2f(unsigned short h) {
    union { unsigned u; float f; } v; v.u = ((unsigned)h) << 16;
    return v.f;
}

// ---------------------------------------------------------------------------
// Prep: split x and Us into bf16 hi/lo. Us emitted in BOTH layouts:
//   ush/usl [k][D][d]  (decode B-frags: d contiguous)
//   uth/utl [k][d][D]  (encode B-frags: D contiguous)
// Also xnorm. bid<512: x part (4 rows/block); else Us part (one 64x64 tile).
// ---------------------------------------------------------------------------
__global__ __launch_bounds__(256) void k_prep(const float* __restrict__ x,
        const float* __restrict__ Us,
        ushort_t* __restrict__ xh, ushort_t* __restrict__ xl,
        ushort_t* __restrict__ uth, ushort_t* __restrict__ utl,
        ushort_t* __restrict__ ush, ushort_t* __restrict__ usl,
        float* __restrict__ xnorm) {
    __shared__ float T[64][68];
    int bid = blockIdx.x, t = threadIdx.x;
    if (bid < 512) {
        int lane = t & 63, w = t >> 6;
        int b = bid * 4 + w;
        const float* xr = x + (size_t)b * Dd;
        float s = 0.f;
#pragma unroll
        for (int seg = 0; seg < 4; ++seg) {
            float4 v = *reinterpret_cast<const float4*>(xr + seg * 256 + lane * 4);
            float ff[4] = {v.x, v.y, v.z, v.w};
            us4 hv, lv;
#pragma unroll
            for (int c = 0; c < 4; ++c) {
                unsigned short h = bfhi(ff[c]);
                hv[c] = h;
                lv[c] = bfhi(ff[c] - bf2f(h));
                s = fmaf(ff[c], ff[c], s);
            }
            size_t off = (size_t)b * Dd + seg * 256 + lane * 4;
            *reinterpret_cast<us4*>(xh + off) = hv;
            *reinterpret_cast<us4*>(xl + off) = lv;
        }
#pragma unroll
        for (int off = 32; off > 0; off >>= 1) s += __shfl_down(s, off, 64);
        if (lane == 0) xnorm[b] = s;
    } else {
        int bid2 = bid - 512;
        int k = bid2 >> 4, Dc = (bid2 & 15) * 64;
        int r = t >> 2, cs = t & 3;
        const float* up = Us + ((size_t)k * Dd + Dc + r) * 64 + cs * 16;
#pragma unroll
        for (int i = 0; i < 4; ++i) {
            float4 v = *reinterpret_cast<const float4*>(up + i * 4);
            float ff[4] = {v.x, v.y, v.z, v.w};
            us4 hv, lv;
#pragma unroll
            for (int c = 0; c < 4; ++c) {
                unsigned short h = bfhi(ff[c]);
                hv[c] = h;
                lv[c] = bfhi(ff[c] - bf2f(h));
                T[cs * 16 + i * 4 + c][r] = ff[c];
            }
            size_t off = ((size_t)k * Dd + Dc + r) * 64 + cs * 16 + i * 4;
            *reinterpret_cast<us4*>(ush + off) = hv;
            *reinterpret_cast<us4*>(usl + off) = lv;
        }
        __syncthreads();
        int n = t >> 2, ds2 = t & 3;
#pragma unroll
        for (int i = 0; i < 4; ++i) {
            us4 hv, lv;
#pragma unroll
            for (int c = 0; c < 4; ++c) {
                float f = T[n][ds2 * 16 + i * 4 + c];
                unsigned short h = bfhi(f);
                hv[c] = h;
                lv[c] = bfhi(f - bf2f(h));
            }
            size_t off = ((size_t)k * 64 + n) * Dd + Dc + ds2 * 16 + i * 4;
            *reinterpret_cast<us4*>(uth + off) = hv;
            *reinterpret_cast<us4*>(utl + off) = lv;
        }
    }
}

// ---------------------------------------------------------------------------
// Fused MFMA encode+decode. Block = 4 waves, each wave owns 32 b-rows.
// One (k, 128-row) tile per block; grid 256; XCD swizzle -> 2 subspaces/XCD.
// Fragment layouts (16x16x32 bf16):
//   A: lane l, reg j -> A[l&15][(l>>4)*8+j]; B: B[(l>>4)*8+j][l&15];
//   C/D: reg r -> D[(l>>4)*4+r][l&15].
// ---------------------------------------------------------------------------
__global__ __launch_bounds__(256) void k_fused(
        const ushort_t* __restrict__ xh, const ushort_t* __restrict__ xl,
        const ushort_t* __restrict__ uth, const ushort_t* __restrict__ utl,
        const ushort_t* __restrict__ ush, const ushort_t* __restrict__ usl,
        float* __restrict__ xhat, float* __restrict__ lterm) {
    __shared__ float zbuf[128][68];
    const int t = threadIdx.x, l = t & 63, w = t >> 6;
    const int lm = l & 15, lg = l >> 4;
    const int bid = blockIdx.x;
    const int sw  = (bid & 7) * 32 + (bid >> 3);   // bijective, 256%8==0
    const int k   = sw >> 4;
    const int b0  = (sw & 15) * 128;
    const int wm  = w * 32;
    const int kb  = lg * 8;

    // ---------------- encode: z = x @ Us[k], 3-pass bf16x2 ----------------
    const ushort_t* xhr0 = xh + (size_t)(b0 + wm + lm) * Dd;
    const ushort_t* xhr1 = xhr0 + (size_t)16 * Dd;
    const ushort_t* xlr0 = xl + (size_t)(b0 + wm + lm) * Dd;
    const ushort_t* xlr1 = xlr0 + (size_t)16 * Dd;
    const ushort_t* bth  = uth + ((size_t)k * 64 + lm) * Dd;
    const ushort_t* btl  = utl + ((size_t)k * 64 + lm) * Dd;

    f32x4 acc[2][4];
#pragma unroll
    for (int i = 0; i < 2; ++i)
#pragma unroll
        for (int j = 0; j < 4; ++j) acc[i][j] = (f32x4){0.f, 0.f, 0.f, 0.f};

#pragma unroll 2
    for (int kc = 0; kc < 32; ++kc) {
        const int ko = kc * 32 + kb;
        short8 ah0 = *reinterpret_cast<const short8*>(xhr0 + ko);
        short8 ah1 = *reinterpret_cast<const short8*>(xhr1 + ko);
        short8 al0 = *reinterpret_cast<const short8*>(xlr0 + ko);
        short8 al1 = *reinterpret_cast<const short8*>(xlr1 + ko);
        short8 bh[4], bl[4];
#pragma unroll
        for (int nt = 0; nt < 4; ++nt) {
            bh[nt] = *reinterpret_cast<const short8*>(bth + (size_t)nt * 16 * Dd + ko);
            bl[nt] = *reinterpret_cast<const short8*>(btl + (size_t)nt * 16 * Dd + ko);
        }
#pragma unroll
        for (int nt = 0; nt < 4; ++nt) {
            acc[0][nt] = __builtin_amdgcn_mfma_f32_16x16x32_bf16(ah0, bh[nt], acc[0][nt], 0, 0, 0);
            acc[0][nt] = __builtin_amdgcn_mfma_f32_16x16x32_bf16(ah0, bl[nt], acc[0][nt], 0, 0, 0);
            acc[0][nt] = __builtin_amdgcn_mfma_f32_16x16x32_bf16(al0, bh[nt], acc[0][nt], 0, 0, 0);
            acc[1][nt] = __builtin_amdgcn_mfma_f32_16x16x32_bf16(ah1, bh[nt], acc[1][nt], 0, 0, 0);
            acc[1][nt] = __builtin_amdgcn_mfma_f32_16x16x32_bf16(ah1, bl[nt], acc[1][nt], 0, 0, 0);
            acc[1][nt] = __builtin_amdgcn_mfma_f32_16x16x32_bf16(al1, bh[nt], acc[1][nt], 0, 0, 0);
        }
    }

    // z -> LDS (C-frag rows lg*4+r; 2-way banks max)
#pragma unroll
    for (int mt = 0; mt < 2; ++mt)
#pragma unroll
        for (int nt = 0; nt < 4; ++nt)
#pragma unroll
            for (int r = 0; r < 4; ++r)
                zbuf[wm + mt * 16 + lg * 4 + r][nt * 16 + lm] = acc[mt][nt][r];
    __syncthreads();

    // z A-frags (rows lm) + znd = z . z_rounded  (exact <x,xhat> surrogate)
    short8 zh[2][2], zl[2][2];
    float znd[2] = {0.f, 0.f};
#pragma unroll
    for (int mt = 0; mt < 2; ++mt)
#pragma unroll
        for (int kc = 0; kc < 2; ++kc) {
            short8 h, lo;
#pragma unroll
            for (int j = 0; j < 8; ++j) {
                float f = zbuf[wm + mt * 16 + lm][kc * 32 + kb + j];
                unsigned short hh = bfhi(f);
                float fr = bf2f(hh);
                unsigned short ll = bfhi(f - fr);
                h[j] = (short)hh; lo[j] = (short)ll;
                znd[mt] = fmaf(f, fr + bf2f(ll), znd[mt]);
            }
            zh[mt][kc] = h; zl[mt][kc] = lo;
        }
#pragma unroll
    for (int mt = 0; mt < 2; ++mt) {
        znd[mt] += __shfl_xor(znd[mt], 16, 64);
        znd[mt] += __shfl_xor(znd[mt], 32, 64);
    }

    // ---------------- decode: xhat = z @ Us[k]^T, 3-pass ----------------
    const ushort_t* bsh = ush + (size_t)k * Dd * 64 + (size_t)lm * 64 + kb;
    const ushort_t* bsl = usl + (size_t)k * Dd * 64 + (size_t)lm * 64 + kb;
    float* xrow = xhat + ((size_t)k * Bb + b0 + wm) * Dd;

    float hat[8];
#pragma unroll
    for (int i = 0; i < 8; ++i) hat[i] = 0.f;

#pragma unroll 2
    for (int nt2 = 0; nt2 < 64; ++nt2) {
        const size_t bo = (size_t)nt2 * 16 * 64;
        short8 bh0 = *reinterpret_cast<const short8*>(bsh + bo);
        short8 bh1 = *reinterpret_cast<const short8*>(bsh + bo + 32);
        short8 bl0 = *reinterpret_cast<const short8*>(bsl + bo);
        short8 bl1 = *reinterpret_cast<const short8*>(bsl + bo + 32);

        f32x4 d0 = (f32x4){0.f, 0.f, 0.f, 0.f};
        f32x4 d1 = (f32x4){0.f, 0.f, 0.f, 0.f};
        d0 = __builtin_amdgcn_mfma_f32_16x16x32_bf16(zh[0][0], bh0, d0, 0, 0, 0);
        d0 = __builtin_amdgcn_mfma_f32_16x16x32_bf16(zh[0][0], bl0, d0, 0, 0, 0);
        d0 = __builtin_amdgcn_mfma_f32_16x16x32_bf16(zl[0][0], bh0, d0, 0, 0, 0);
        d0 = __builtin_amdgcn_mfma_f32_16x16x32_bf16(zh[0][1], bh1, d0, 0, 0, 0);
        d0 = __builtin_amdgcn_mfma_f32_16x16x32_bf16(zh[0][1], bl1, d0, 0, 0, 0);
        d0 = __builtin_amdgcn_mfma_f32_16x16x32_bf16(zl[0][1], bh1, d0, 0, 0, 0);
        d1 = __builtin_amdgcn_mfma_f32_16x16x32_bf16(zh[1][0], bh0, d1, 0, 0, 0);
        d1 = __builtin_amdgcn_mfma_f32_16x16x32_bf16(zh[1][0], bl0, d1, 0, 0, 0);
        d1 = __builtin_amdgcn_mfma_f32_16x16x32_bf16(zl[1][0], bh0, d1, 0, 0, 0);
        d1 = __builtin_amdgcn_mfma_f32_16x16x32_bf16(zh[1][1], bh1, d1, 0, 0, 0);
        d1 = __builtin_amdgcn_mfma_f32_16x16x32_bf16(zh[1][1], bl1, d1, 0, 0, 0);
        d1 = __builtin_amdgcn_mfma_f32_16x16x32_bf16(zl[1][1], bh1, d1, 0, 0, 0);

#pragma unroll
        for (int r = 0; r < 4; ++r) {
            xrow[(size_t)(lg * 4 + r) * Dd + nt2 * 16 + lm] = d0[r];
            hat[r] = fmaf(d0[r], d0[r], hat[r]);
            xrow[(size_t)(16 + lg * 4 + r) * Dd + nt2 * 16 + lm] = d1[r];
            hat[4 + r] = fmaf(d1[r], d1[r], hat[4 + r]);
        }
    }

#pragma unroll
    for (int i = 0; i < 8; ++i) {
        hat[i] += __shfl_xor(hat[i], 1, 64);
        hat[i] += __shfl_xor(hat[i], 2, 64);
        hat[i] += __shfl_xor(hat[i], 4, 64);
        hat[i] += __shfl_xor(hat[i], 8, 64);
    }
#pragma unroll
    for (int mt = 0; mt < 2; ++mt)
#pragma unroll
        for (int r = 0; r < 4; ++r) {
            float zv = __shfl(znd[mt], lg * 4 + r, 64);   // all lanes execute
            if (lm == 0)
                lterm[(size_t)k * Bb + b0 + wm + mt * 16 + lg * 4 + r] =
                    hat[mt * 4 + r] - 2.f * zv;
        }
}

// ---------------------------------------------------------------------------
// Assign + finalize in one block (reads 136 KB; L3-resident).
// ---------------------------------------------------------------------------
__global__ __launch_bounds__(1024) void k_assign(const float* __restrict__ xnorm,
                                                 const float* __restrict__ lterm,
                                                 const float* __restrict__ c_mean,
                                                 float* __restrict__ c,
                                                 float* __restrict__ c_mean_new,
                                                 float* __restrict__ obj) {
    __shared__ float cnt[Kk];
    __shared__ float objacc;
    const int t = threadIdx.x;
    if (t < Kk) cnt[t] = 0.f;
    if (t == 0) objacc = 0.f;
    __syncthreads();

    float lobj = 0.f;
    for (int b = t; b < Bb; b += 1024) {
        float xn = xnorm[b];
        float best = 3.4e38f;
        int bi = 0;
#pragma unroll
        for (int k = 0; k < Kk; ++k) {
            float lv = xn + lterm[k * Bb + b];
            if (lv < best) { best = lv; bi = k; }   // strict < == first argmin
        }
#pragma unroll
        for (int j = 0; j < 4; ++j) {
            float4 o;
            o.x = (bi == j * 4 + 0) ? 1.f : 0.f;
            o.y = (bi == j * 4 + 1) ? 1.f : 0.f;
            o.z = (bi == j * 4 + 2) ? 1.f : 0.f;
            o.w = (bi == j * 4 + 3) ? 1.f : 0.f;
            *reinterpret_cast<float4*>(&c[(size_t)b * Kk + j * 4]) = o;
        }
        atomicAdd(&cnt[bi], 1.f);
        lobj += best;
    }
#pragma unroll
    for (int off = 32; off > 0; off >>= 1) lobj += __shfl_down(lobj, off, 64);
    if ((t & 63) == 0) atomicAdd(&objacc, lobj);
    __syncthreads();

    if (t < Kk) c_mean_new[t] = 0.9f * c_mean[t] + 0.1f * (cnt[t] * (1.f / Bb));
    if (t == 0) obj[0] = objacc * (1.f / Bb);
}

// ---------------------------------------------------------------------------
extern "C" void kernel_launch(void* const* d_in, const int* in_sizes, int n_in,
                              void* d_out, int out_size, void* d_ws, size_t ws_size,
                              hipStream_t stream) {
    const float* x      = (const float*)d_in[0];
    const float* Us     = (const float*)d_in[1];
    const float* c_mean = (const float*)d_in[2];

    float* out        = (float*)d_out;
    float* xhat       = out;                              // K*B*D
    float* c          = out + (size_t)Kk * Bb * Dd;       // B*K
    float* c_mean_new = c + (size_t)Bb * Kk;              // K
    float* obj        = c_mean_new + Kk;                  // 1

    // workspace: 16.2 MB
    ushort_t* xh  = (ushort_t*)d_ws;                      // 4 MB
    ushort_t* xl  = xh + (size_t)Bb * Dd;                 // 4 MB
    ushort_t* uth = xl + (size_t)Bb * Dd;                 // 2 MB
    ushort_t* utl = uth + (size_t)Kk * 64 * Dd;           // 2 MB
    ushort_t* ush = utl + (size_t)Kk * 64 * Dd;           // 2 MB
    ushort_t* usl = ush + (size_t)Kk * Dd * 64;           // 2 MB
    float* xnorm  = (float*)(usl + (size_t)Kk * Dd * 64); // 8 KB
    float* lterm  = xnorm + Bb;                           // 128 KB

    k_prep  <<<768, 256, 0, stream>>>(x, Us, xh, xl, uth, utl, ush, usl, xnorm);
    k_fused <<<256, 256, 0, stream>>>(xh, xl, uth, utl, ush, usl, xhat, lterm);
    k_assign<<<1, 1024, 0, stream>>>(xnorm, lterm, c_mean, c, c_mean_new, obj);
}